// Round 8
// baseline (85.674 us; speedup 1.0000x reference)
//
#include <hip/hip_runtime.h>
#include <hip/hip_fp16.h>

typedef __bf16 bf16x8 __attribute__((ext_vector_type(8)));
typedef float floatx16 __attribute__((ext_vector_type(16)));
typedef unsigned int uint;
typedef unsigned short ushort;
typedef uint  uintx4  __attribute__((ext_vector_type(4)));
typedef uint  uintx2  __attribute__((ext_vector_type(2)));
typedef float floatx4 __attribute__((ext_vector_type(4)));

constexpr int Mdim = 256, Ndim = 8192, Kdim = 8192;
constexpr int BN = 64, BK = 64, KSPLIT = 4;
constexpr int KS = Kdim / KSPLIT;    // 2048 per block
constexpr int NT = KS / BK;          // 32 K-steps
constexpr int KB = Kdim / 256;       // 32 q4k blocks per weight row

union U4 { uint u[2]; uintx2 v; };

__device__ __forceinline__ uint cvtpk(float lo, float hi) {
  uint r; asm("v_cvt_pk_bf16_f32 %0, %1, %2" : "=v"(r) : "v"(lo), "v"(hi));
  return r;
}

// explicit global (addrspace(1)) loads: guaranteed global_load_* (vmcnt-only,
// never flat). flat_* would increment lgkmcnt and get drained at our barrier.
template <typename T>
__device__ __forceinline__ T gld(const void* p) {
  return *(const __attribute__((address_space(1))) T*)p;
}

// B LDS: 64 rows x 64 ushort (128B row); XOR-swizzle 16B chunks across banks
__device__ __forceinline__ int bswz(int row, int ch) {
  return row * 64 + ((ch ^ (row & 7)) << 3);
}

template<bool PRE>
__global__ __launch_bounds__(512, 2)
void q4k_gemm(const float* __restrict__ x, const bf16x8* __restrict__ xbf,
              const int* __restrict__ qw, const float* __restrict__ bias,
              float* __restrict__ out)
{
  __shared__ ushort Bb[2][BN * 64];   // 8 KB each, double-buffered

  const int tid = threadIdx.x;
  const int bid = blockIdx.x;
  // bijective XCD swizzle (512 blocks): ks-siblings of one n-tile co-XCD
  const int l  = (bid & 7) * 64 + (bid >> 3);
  const int nb = l >> 2;              // 0..127
  const int ks = l & 3;
  const int n0 = nb * BN;
  const int ks8 = ks * (KS >> 8);

  const int sr = tid >> 3;   // B staging row 0..63 (8 threads per row)
  const int sq = tid & 7;    // 4-int slice within the 32-int qs group

  const int lane = tid & 63;
  const int wave = tid >> 6;          // 0..7
  const int wn   = wave & 1;          // n-half (32 cols)
  const int mb0  = (wave >> 1) * 2;   // two 32-row m-frags per wave
  const int brow = lane & 31;
  const int bco  = lane >> 5;

  const int* bp0 = qw + (n0 + sr) * (KB * 144);
  const bf16x8* xA0 = PRE ? (xbf + ((mb0    ) * 512 + ks * 128) * 64 + lane) : nullptr;
  const bf16x8* xA1 = PRE ? (xbf + ((mb0 + 1) * 512 + ks * 128) * 64 + lane) : nullptr;

  uintx4 R[4];                           // 3-phase-deep qs prefetch ring
  uintx4 Mdd[2], M0[2], M1[2], M2[2];    // meta, 4-step granularity, 2 slots
  uintx2 pqL, pqH;
  bf16x8 aA[8], aB[8];
  floatx16 acc00 = {}, acc10 = {};

  auto gloadB = [&](int s2, int rs, int ms, bool meta) {
    const int* bp = bp0 + (ks8 + (s2 >> 2)) * 144;
    const int* qp = bp + 16 + (s2 & 3) * 32 + sq * 4;
    R[rs] = gld<uintx4>(qp);
    if (meta) {
      Mdd[ms] = gld<uintx4>(bp);
      M0[ms]  = gld<uintx4>(bp + 4);
      M1[ms]  = gld<uintx4>(bp + 8);
      M2[ms]  = gld<uintx4>(bp + 12);
    }
  };

  auto gloadA = [&](int t, bf16x8 (&A)[8]) {
    if constexpr (PRE) {
      const int f = t * 4 * 64;
      #pragma unroll
      for (int kk = 0; kk < 4; ++kk) {
        A[kk]     = gld<bf16x8>(xA0 + f + kk * 64);
        A[4 + kk] = gld<bf16x8>(xA1 + f + kk * 64);
      }
    } else {
      const int kg = ks * KS + t * BK + bco * 8;
      #pragma unroll
      for (int kk = 0; kk < 4; ++kk) {
        const float* fA = x + (mb0 * 32 + brow) * Kdim + kg + kk * 16;
        const float* fB = x + ((mb0 + 1) * 32 + brow) * Kdim + kg + kk * 16;
        const floatx4 p0 = gld<floatx4>(fA), p1 = gld<floatx4>(fA + 4);
        const floatx4 q0 = gld<floatx4>(fB), q1 = gld<floatx4>(fB + 4);
        union { uint u[4]; bf16x8 v; } ua, ub;
        ua.u[0] = cvtpk(p0.x, p0.y); ua.u[1] = cvtpk(p0.z, p0.w);
        ua.u[2] = cvtpk(p1.x, p1.y); ua.u[3] = cvtpk(p1.z, p1.w);
        ub.u[0] = cvtpk(q0.x, q0.y); ub.u[1] = cvtpk(q0.z, q0.w);
        ub.u[2] = cvtpk(q1.x, q1.y); ub.u[3] = cvtpk(q1.z, q1.w);
        A[kk] = ua.v; A[4 + kk] = ub.v;
      }
    }
  };

  auto dequant = [&](int c, int rs, int ms) {
    const uintx4 dd = Mdd[ms];
    const float d  = __half2float(__ushort_as_half((ushort)((dd.x & 255u) | ((dd.y & 255u) << 8))));
    const float dm = __half2float(__ushort_as_half((ushort)((dd.z & 255u) | ((dd.w & 255u) << 8))));
    const uintx4 s0 = M0[ms], s1 = M1[ms], s2 = M2[ms];
    uint scA, scB, mnA, mnB;
    if (c == 0)      { scA = s0.x & 63u; scB = s0.y & 63u; mnA = s1.x & 63u; mnB = s1.y & 63u; }
    else if (c == 1) { scA = s0.z & 63u; scB = s0.w & 63u; mnA = s1.z & 63u; mnB = s1.w & 63u; }
    else if (c == 2) {
      scA = (s2.x & 15u) | ((s0.x >> 2) & 48u); scB = (s2.y & 15u) | ((s0.y >> 2) & 48u);
      mnA = (s2.x >> 4)  | ((s1.x >> 2) & 48u); mnB = (s2.y >> 4)  | ((s1.y >> 2) & 48u);
    } else {
      scA = (s2.z & 15u) | ((s0.z >> 2) & 48u); scB = (s2.w & 15u) | ((s0.w >> 2) & 48u);
      mnA = (s2.z >> 4)  | ((s1.z >> 2) & 48u); mnB = (s2.w >> 4)  | ((s1.w >> 2) & 48u);
    }
    const float dlA = d * (float)scA, mlA = dm * (float)mnA;
    const float dlB = d * (float)scB, mlB = dm * (float)mnB;
    const uintx4 qv = R[rs];
    const float w0 = fmaf(dlA, (float)(qv.x & 15u), -mlA);
    const float w1 = fmaf(dlA, (float)(qv.y & 15u), -mlA);
    const float w2 = fmaf(dlA, (float)(qv.z & 15u), -mlA);
    const float w3 = fmaf(dlA, (float)(qv.w & 15u), -mlA);
    const float h0 = fmaf(dlB, (float)(qv.x >> 4), -mlB);
    const float h1 = fmaf(dlB, (float)(qv.y >> 4), -mlB);
    const float h2 = fmaf(dlB, (float)(qv.z >> 4), -mlB);
    const float h3 = fmaf(dlB, (float)(qv.w >> 4), -mlB);
    pqL.x = cvtpk(w0, w1); pqL.y = cvtpk(w2, w3);
    pqH.x = cvtpk(h0, h1); pqH.y = cvtpk(h2, h3);
  };

  auto bwrite = [&](int bufi) {
    // low nibbles -> chunk sq>>1 (k = [4*sq, 4*sq+4)); high -> chunk 4+(sq>>1)
    *(uintx2*)&Bb[bufi][bswz(sr, (sq >> 1))     + (sq & 1) * 4] = pqL;
    *(uintx2*)&Bb[bufi][bswz(sr, 4 + (sq >> 1)) + (sq & 1) * 4] = pqH;
  };

  auto mstep = [&](int bufi, const bf16x8 (&A)[8]) {
    #pragma unroll
    for (int kk = 0; kk < 4; ++kk) {
      const bf16x8 bq = *(const bf16x8*)&Bb[bufi][bswz(wn * 32 + brow, kk * 2 + bco)];
      acc00 = __builtin_amdgcn_mfma_f32_32x32x16_bf16(A[kk],     bq, acc00, 0, 0, 0);
      acc10 = __builtin_amdgcn_mfma_f32_32x32x16_bf16(A[4 + kk], bq, acc10, 0, 0, 0);
    }
  };

  // prologue: qs for steps 0..3, meta slot0 (steps 0-3), A for steps 0,1
  gloadB(0, 0, 0, true);
  gloadB(1, 1, 0, false);
  gloadB(2, 2, 0, false);
  gloadB(3, 3, 0, false);
  gloadA(0, aA);
  gloadA(1, aB);
  dequant(0, 0, 0);
  bwrite(0);
  asm volatile("s_waitcnt lgkmcnt(0)" ::: "memory");
  __builtin_amdgcn_s_barrier();
  __builtin_amdgcn_sched_barrier(0);

  // steady state: one raw barrier/step; vmcnt never drained in-loop.
  // qs cover = 3 phases (R ring of 4); meta cover = 3-6 phases; A cover = 2.
  #define PH(u, CUR) {                                                       \
    const int s_ = base + (u);                                               \
    if (s_ + 4 < NT) gloadB(s_ + 4, (u) & 3, (((u) + 4) >> 2) & 1,           \
                            (((u) + 4) & 3) == 0);                           \
    if (s_ + 1 < NT) {                                                       \
      dequant(((u) + 1) & 3, ((u) + 1) & 3, (((u) + 1) >> 2) & 1);           \
      bwrite(((u) + 1) & 1);                                                 \
    }                                                                        \
    __builtin_amdgcn_s_setprio(1);                                           \
    mstep((u) & 1, CUR);                                                     \
    __builtin_amdgcn_s_setprio(0);                                           \
    if (s_ + 2 < NT) gloadA(s_ + 2, CUR);                                    \
    asm volatile("s_waitcnt lgkmcnt(0)" ::: "memory");                       \
    __builtin_amdgcn_s_barrier();                                            \
    __builtin_amdgcn_sched_barrier(0);                                       \
  }

  for (int base = 0; base < NT; base += 8) {
    PH(0, aA) PH(1, aB) PH(2, aA) PH(3, aB)
    PH(4, aA) PH(5, aB) PH(6, aA) PH(7, aB)
  }
  #undef PH

  // epilogue: D layout col=lane&31, row=(r&3)+8*(r>>2)+4*(lane>>5)  [m74/m101]
  const int gn = n0 + wn * 32 + (lane & 31);
  const float bv = (ks == 0) ? bias[gn] : 0.0f;
  const int mrow = (wave >> 1) * 64 + 4 * (lane >> 5);
  #pragma unroll
  for (int r = 0; r < 16; ++r) {
    const int m = mrow + (r & 3) + 8 * (r >> 2);
    atomicAdd(&out[m * Ndim + gn], acc00[r] + bv);
    atomicAdd(&out[(m + 32) * Ndim + gn], acc10[r] + bv);
  }
}

// zero d_out (atomic accumulate target) and optionally pre-tile x -> bf16
// MFMA-fragment layout: xb[(mb*512+kb)*64+lane] = 16B frag slice,
// m = mb*32+(lane&31), k = kb*16+(lane>>5)*8
template<bool DOCVT>
__global__ __launch_bounds__(256)
void prep(const float* __restrict__ x, uintx4* __restrict__ xb,
          floatx4* __restrict__ out)
{
  const int gid = blockIdx.x * 256 + threadIdx.x;
  out[gid * 2]     = floatx4{0.f, 0.f, 0.f, 0.f};
  out[gid * 2 + 1] = floatx4{0.f, 0.f, 0.f, 0.f};
  if (DOCVT) {
    const int lane = gid & 63;
    const int m = ((gid >> 15) * 32) + (lane & 31);
    const int k = (((gid >> 6) & 511) * 16) + (lane >> 5) * 8;
    const floatx4 f0 = gld<floatx4>(x + m * Kdim + k);
    const floatx4 f1 = gld<floatx4>(x + m * Kdim + k + 4);
    uintx4 st;
    st.x = cvtpk(f0.x, f0.y); st.y = cvtpk(f0.z, f0.w);
    st.z = cvtpk(f1.x, f1.y); st.w = cvtpk(f1.z, f1.w);
    xb[gid] = st;
  }
}

extern "C" void kernel_launch(void* const* d_in, const int* in_sizes, int n_in,
                              void* d_out, int out_size, void* d_ws, size_t ws_size,
                              hipStream_t stream) {
  (void)in_sizes; (void)n_in; (void)out_size;
  const float* x    = (const float*)d_in[0];
  const int*   qw   = (const int*)d_in[1];
  const float* bias = (const float*)d_in[2];
  float* out = (float*)d_out;

  const size_t need = (size_t)Mdim * Kdim * 2;   // 4 MB bf16 fragment tiles
  if (ws_size >= need) {
    prep<true><<<1024, 256, 0, stream>>>(x, (uintx4*)d_ws, (floatx4*)out);
    q4k_gemm<true><<<512, 512, 0, stream>>>(x, (const bf16x8*)d_ws, qw, bias, out);
  } else {
    prep<false><<<1024, 256, 0, stream>>>(x, nullptr, (floatx4*)out);
    q4k_gemm<false><<<512, 512, 0, stream>>>(x, nullptr, qw, bias, out);
  }
}

// Round 9
// 70.915 us; speedup vs baseline: 1.2081x; 1.2081x over previous
//
#include <hip/hip_runtime.h>
#include <hip/hip_fp16.h>

typedef __bf16 bf16x8 __attribute__((ext_vector_type(8)));
typedef float floatx16 __attribute__((ext_vector_type(16)));
typedef unsigned int uint;
typedef unsigned short ushort;
typedef uint  uintx4  __attribute__((ext_vector_type(4)));
typedef float floatx4 __attribute__((ext_vector_type(4)));

constexpr int Mdim = 256, Ndim = 8192, Kdim = 8192;
constexpr int BN = 64, KSPLIT = 4;
constexpr int KS = Kdim / KSPLIT;    // 2048 k per block
constexpr int NT = KS / 64;          // 32 64k-steps (2 per barrier phase)
constexpr int KB = Kdim / 256;       // 32 superblocks per weight row

union U8 { uint u[4]; bf16x8 v; };

__device__ __forceinline__ uint cvtpk(float lo, float hi) {
  uint r; asm("v_cvt_pk_bf16_f32 %0, %1, %2" : "=v"(r) : "v"(lo), "v"(hi));
  return r;
}

// explicit global (addrspace(1)) loads: guaranteed global_load_* (vmcnt-only)
template <typename T>
__device__ __forceinline__ T gld(const void* p) {
  return *(const __attribute__((address_space(1))) T*)p;
}

// B LDS: 64 rows x 128 ushort (256B row); 16 chunks of 16B, XOR-swizzled
// (round-2-verified 16-chunk variant)
__device__ __forceinline__ int bswz(int row, int ch) {
  return row * 128 + ((ch ^ (row & 15)) << 3);
}

template<bool PRE>
__global__ __launch_bounds__(256, 2)
void q4k_gemm(const float* __restrict__ x, const bf16x8* __restrict__ xbf,
              const int* __restrict__ qw, const float* __restrict__ bias,
              float* __restrict__ out)
{
  __shared__ ushort Bb[2][BN * 128];   // 16 KB each, double-buffered

  const int tid = threadIdx.x;
  const int bid = blockIdx.x;
  // bijective XCD swizzle (512 blocks): ks-siblings of one n-tile co-XCD
  const int l  = (bid & 7) * 64 + (bid >> 3);
  const int nb = l >> 2;              // 0..127
  const int ks = l & 3;
  const int n0 = nb * BN;
  const int ks8 = ks * (KS >> 8);

  const int sr = tid >> 2;   // B staging row 0..63
  const int sq = tid & 3;    // 8-int slice within the 32-int qs group

  const int lane = tid & 63;
  const int wave = tid >> 6;
  const int mb0  = wave * 2;          // two 32-row m-frags per wave
  const int brow = lane & 31;
  const int bco  = lane >> 5;

  const int* bp0 = qw + (n0 + sr) * (KB * 144);
  const bf16x8* xA0 = PRE ? (xbf + ((mb0    ) * 512 + ks * 128) * 64 + lane) : nullptr;
  const bf16x8* xA1 = PRE ? (xbf + ((mb0 + 1) * 512 + ks * 128) * 64 + lane) : nullptr;

  uintx4 R[4][2];                        // qs ring: 4 steps deep
  uintx4 Mdd[2], M0[2], M1[2], M2[2];    // meta: 2 superblock slots
  U8 pqL, pqH;
  bf16x8 aA[8], aB[8];
  floatx16 acc00 = {}, acc01 = {}, acc10 = {}, acc11 = {};

  auto gloadB = [&](int s2, int rs) {
    const int* qp = bp0 + (ks8 + (s2 >> 2)) * 144 + 16 + (s2 & 3) * 32 + sq * 8;
    R[rs][0] = gld<uintx4>(qp);
    R[rs][1] = gld<uintx4>(qp + 4);
  };

  auto mload = [&](int sbrel, int ms) {
    const int* bp = bp0 + (ks8 + sbrel) * 144;
    Mdd[ms] = gld<uintx4>(bp);
    M0[ms]  = gld<uintx4>(bp + 4);
    M1[ms]  = gld<uintx4>(bp + 8);
    M2[ms]  = gld<uintx4>(bp + 12);
  };

  auto gloadA = [&](int t, bf16x8 (&A)[8]) {
    if constexpr (PRE) {
      const int f = t * 4 * 64;
      #pragma unroll
      for (int kk = 0; kk < 4; ++kk) {
        A[kk]     = gld<bf16x8>(xA0 + f + kk * 64);
        A[4 + kk] = gld<bf16x8>(xA1 + f + kk * 64);
      }
    } else {
      const int kg = ks * KS + t * 64 + bco * 8;
      #pragma unroll
      for (int kk = 0; kk < 4; ++kk) {
        const float* fA = x + (mb0 * 32 + brow) * Kdim + kg + kk * 16;
        const float* fB = x + ((mb0 + 1) * 32 + brow) * Kdim + kg + kk * 16;
        const floatx4 p0 = gld<floatx4>(fA), p1 = gld<floatx4>(fA + 4);
        const floatx4 q0 = gld<floatx4>(fB), q1 = gld<floatx4>(fB + 4);
        U8 ua, ub;
        ua.u[0] = cvtpk(p0.x, p0.y); ua.u[1] = cvtpk(p0.z, p0.w);
        ua.u[2] = cvtpk(p1.x, p1.y); ua.u[3] = cvtpk(p1.z, p1.w);
        ub.u[0] = cvtpk(q0.x, q0.y); ub.u[1] = cvtpk(q0.z, q0.w);
        ub.u[2] = cvtpk(q1.x, q1.y); ub.u[3] = cvtpk(q1.z, q1.w);
        A[kk] = ua.v; A[4 + kk] = ub.v;
      }
    }
  };

  auto dequant = [&](int c, int rs, int ms) {
    const uintx4 dd = Mdd[ms];
    const float d  = __half2float(__ushort_as_half((ushort)((dd.x & 255u) | ((dd.y & 255u) << 8))));
    const float dm = __half2float(__ushort_as_half((ushort)((dd.z & 255u) | ((dd.w & 255u) << 8))));
    const uintx4 s0 = M0[ms], s1 = M1[ms], s2 = M2[ms];
    uint scA, scB, mnA, mnB;
    if (c == 0)      { scA = s0.x & 63u; scB = s0.y & 63u; mnA = s1.x & 63u; mnB = s1.y & 63u; }
    else if (c == 1) { scA = s0.z & 63u; scB = s0.w & 63u; mnA = s1.z & 63u; mnB = s1.w & 63u; }
    else if (c == 2) {
      scA = (s2.x & 15u) | ((s0.x >> 2) & 48u); scB = (s2.y & 15u) | ((s0.y >> 2) & 48u);
      mnA = (s2.x >> 4)  | ((s1.x >> 2) & 48u); mnB = (s2.y >> 4)  | ((s1.y >> 2) & 48u);
    } else {
      scA = (s2.z & 15u) | ((s0.z >> 2) & 48u); scB = (s2.w & 15u) | ((s0.w >> 2) & 48u);
      mnA = (s2.z >> 4)  | ((s1.z >> 2) & 48u); mnB = (s2.w >> 4)  | ((s1.w >> 2) & 48u);
    }
    const float dlA = d * (float)scA, mlA = dm * (float)mnA;
    const float dlB = d * (float)scB, mlB = dm * (float)mnB;
    float wl[8], wh[8];
    #pragma unroll
    for (int h = 0; h < 2; ++h) {
      const uintx4 qv = R[rs][h];
      wl[h*4+0] = fmaf(dlA, (float)(qv.x & 15u), -mlA);
      wl[h*4+1] = fmaf(dlA, (float)(qv.y & 15u), -mlA);
      wl[h*4+2] = fmaf(dlA, (float)(qv.z & 15u), -mlA);
      wl[h*4+3] = fmaf(dlA, (float)(qv.w & 15u), -mlA);
      wh[h*4+0] = fmaf(dlB, (float)(qv.x >> 4), -mlB);
      wh[h*4+1] = fmaf(dlB, (float)(qv.y >> 4), -mlB);
      wh[h*4+2] = fmaf(dlB, (float)(qv.z >> 4), -mlB);
      wh[h*4+3] = fmaf(dlB, (float)(qv.w >> 4), -mlB);
    }
    #pragma unroll
    for (int p = 0; p < 4; ++p) {
      pqL.u[p] = cvtpk(wl[2*p], wl[2*p+1]);
      pqH.u[p] = cvtpk(wh[2*p], wh[2*p+1]);
    }
  };

  auto bwrite = [&](int bufi, int h) {
    // within half h: lo nibbles -> chunk h*8+sq, hi nibbles -> chunk h*8+4+sq
    *(bf16x8*)&Bb[bufi][bswz(sr, h * 8 + sq)]     = pqL.v;
    *(bf16x8*)&Bb[bufi][bswz(sr, h * 8 + 4 + sq)] = pqH.v;
  };

  auto mstep = [&](int bufi, int h, const bf16x8 (&A)[8]) {
    #pragma unroll
    for (int kk = 0; kk < 4; ++kk) {
      const bf16x8 bq0 = *(const bf16x8*)&Bb[bufi][bswz(brow,      h * 8 + kk * 2 + bco)];
      const bf16x8 bq1 = *(const bf16x8*)&Bb[bufi][bswz(brow + 32, h * 8 + kk * 2 + bco)];
      acc00 = __builtin_amdgcn_mfma_f32_32x32x16_bf16(A[kk],     bq0, acc00, 0, 0, 0);
      acc01 = __builtin_amdgcn_mfma_f32_32x32x16_bf16(A[kk],     bq1, acc01, 0, 0, 0);
      acc10 = __builtin_amdgcn_mfma_f32_32x32x16_bf16(A[4 + kk], bq0, acc10, 0, 0, 0);
      acc11 = __builtin_amdgcn_mfma_f32_32x32x16_bf16(A[4 + kk], bq1, acc11, 0, 0, 0);
    }
  };

  // prologue: meta sb0/sb1; qs steps 0..3; A steps 0,1; stage buf0 (steps 0,1)
  mload(0, 0); mload(1, 1);
  gloadB(0, 0); gloadB(1, 1); gloadB(2, 2); gloadB(3, 3);
  gloadA(0, aA); gloadA(1, aB);
  dequant(0, 0, 0); bwrite(0, 0);
  dequant(1, 1, 0); bwrite(0, 1);
  asm volatile("s_waitcnt lgkmcnt(0)" ::: "memory");
  __builtin_amdgcn_s_barrier();
  __builtin_amdgcn_sched_barrier(0);

  // 16 barrier phases; phase p computes steps {2p,2p+1} from buf(p&1),
  // stages steps {2p+2,2p+3} into buf^1, prefetches qs for {2p+4,2p+5}.
  // vmcnt is never drained in-loop; lgkmcnt(0) only (LDS visibility).
  #define MLOADJ(j)                                                          \
    if ((j) == 1) { const int sb_ = B / 2 + 2; if (sb_ < 8) mload(sb_, 0); } \
    else if ((j) == 3) { const int sb_ = B / 2 + 3; if (sb_ < 8) mload(sb_, 1); }

  #define PH2(j) {                                                           \
    const int p_ = B + (j);                                                  \
    const int s1_ = 2 * p_ + 2, s2_ = 2 * p_ + 3;                            \
    if (s1_ < NT) { dequant((2*(j)+2)&3, (2*(j)+2)&3, (((j)+1)>>1)&1);       \
                    bwrite(((j)&1)^1, 0); }                                  \
    if (s2_ < NT) { dequant((2*(j)+3)&3, (2*(j)+3)&3, (((j)+1)>>1)&1);       \
                    bwrite(((j)&1)^1, 1); }                                  \
    if (s1_ + 2 < NT) gloadB(s1_ + 2, (2*(j)+4)&3);                          \
    if (s2_ + 2 < NT) gloadB(s2_ + 2, (2*(j)+5)&3);                          \
    MLOADJ(j)                                                                \
    __builtin_amdgcn_s_setprio(1);                                           \
    mstep((j)&1, 0, aA);                                                     \
    __builtin_amdgcn_s_setprio(0);                                           \
    if (s1_ < NT) gloadA(s1_, aA);                                           \
    __builtin_amdgcn_s_setprio(1);                                           \
    mstep((j)&1, 1, aB);                                                     \
    __builtin_amdgcn_s_setprio(0);                                           \
    if (s2_ < NT) gloadA(s2_, aB);                                           \
    asm volatile("s_waitcnt lgkmcnt(0)" ::: "memory");                       \
    __builtin_amdgcn_s_barrier();                                            \
    __builtin_amdgcn_sched_barrier(0);                                       \
  }

  for (int i = 0; i < 4; ++i) {
    const int B = i * 4;
    PH2(0) PH2(1) PH2(2) PH2(3)
  }
  #undef PH2
  #undef MLOADJ

  // epilogue: D layout col=lane&31, row=(r&3)+8*(r>>2)+4*(lane>>5)  [m74/m101]
  const int gn0 = n0 + (lane & 31);
  const int gn1 = gn0 + 32;
  const float bv0 = (ks == 0) ? bias[gn0] : 0.0f;
  const float bv1 = (ks == 0) ? bias[gn1] : 0.0f;
  const int mrow = wave * 64 + 4 * (lane >> 5);
  #pragma unroll
  for (int r = 0; r < 16; ++r) {
    const int m = mrow + (r & 3) + 8 * (r >> 2);
    atomicAdd(&out[m * Ndim + gn0], acc00[r] + bv0);
    atomicAdd(&out[m * Ndim + gn1], acc01[r] + bv1);
    atomicAdd(&out[(m + 32) * Ndim + gn0], acc10[r] + bv0);
    atomicAdd(&out[(m + 32) * Ndim + gn1], acc11[r] + bv1);
  }
}

// zero d_out (atomic accumulate target) and optionally pre-tile x -> bf16
// MFMA-fragment layout: xb[(mb*512+kb)*64+lane] = 16B frag slice,
// m = mb*32+(lane&31), k = kb*16+(lane>>5)*8
template<bool DOCVT>
__global__ __launch_bounds__(256)
void prep(const float* __restrict__ x, uintx4* __restrict__ xb,
          floatx4* __restrict__ out)
{
  const int gid = blockIdx.x * 256 + threadIdx.x;
  out[gid * 2]     = floatx4{0.f, 0.f, 0.f, 0.f};
  out[gid * 2 + 1] = floatx4{0.f, 0.f, 0.f, 0.f};
  if (DOCVT) {
    const int lane = gid & 63;
    const int m = ((gid >> 15) * 32) + (lane & 31);
    const int k = (((gid >> 6) & 511) * 16) + (lane >> 5) * 8;
    const floatx4 f0 = gld<floatx4>(x + m * Kdim + k);
    const floatx4 f1 = gld<floatx4>(x + m * Kdim + k + 4);
    uintx4 st;
    st.x = cvtpk(f0.x, f0.y); st.y = cvtpk(f0.z, f0.w);
    st.z = cvtpk(f1.x, f1.y); st.w = cvtpk(f1.z, f1.w);
    xb[gid] = st;
  }
}

extern "C" void kernel_launch(void* const* d_in, const int* in_sizes, int n_in,
                              void* d_out, int out_size, void* d_ws, size_t ws_size,
                              hipStream_t stream) {
  (void)in_sizes; (void)n_in; (void)out_size;
  const float* x    = (const float*)d_in[0];
  const int*   qw   = (const int*)d_in[1];
  const float* bias = (const float*)d_in[2];
  float* out = (float*)d_out;

  const size_t need = (size_t)Mdim * Kdim * 2;   // 4 MB bf16 fragment tiles
  if (ws_size >= need) {
    prep<true><<<1024, 256, 0, stream>>>(x, (uintx4*)d_ws, (floatx4*)out);
    q4k_gemm<true><<<512, 256, 0, stream>>>(x, (const bf16x8*)d_ws, qw, bias, out);
  } else {
    prep<false><<<1024, 256, 0, stream>>>(x, nullptr, (floatx4*)out);
    q4k_gemm<false><<<512, 256, 0, stream>>>(x, nullptr, qw, bias, out);
  }
}